// Round 1
// baseline (1104.231 us; speedup 1.0000x reference)
//
#include <hip/hip_runtime.h>

#define HH 128
#define GG 256

// ---------------------------------------------------------------- setup
__global__ __launch_bounds__(256) void setup_k(const float* __restrict__ x,
                                               float* __restrict__ z0,
                                               float* __restrict__ pooled, int n)
{
    int i = blockIdx.x * 256 + threadIdx.x;
    if (i < GG * HH) pooled[i] = 0.f;
    if (i < n) z0[i] = x[i];
}

// ------------------------------------------------- layer0 scalar edge agg
__global__ __launch_bounds__(256) void edge0_k(const float* __restrict__ x,
                                               const int* __restrict__ src,
                                               const int* __restrict__ dst,
                                               float* __restrict__ z0, int ne)
{
    int e = blockIdx.x * 256 + threadIdx.x;
    if (e < ne) unsafeAtomicAdd(&z0[dst[e]], x[src[e]]);
}

// -------------------------------------- layer0: t = relu(z0 * W1row + b1)
__global__ __launch_bounds__(256) void expand0_k(const float* __restrict__ z0,
                                                 const float* __restrict__ W1,
                                                 const float* __restrict__ b1,
                                                 float* __restrict__ t, int total)
{
    int stride = gridDim.x * 256;
    for (int i = blockIdx.x * 256 + threadIdx.x; i < total; i += stride) {
        int n = i >> 7, j = i & (HH - 1);
        t[i] = fmaxf(fmaf(z0[n], W1[j], b1[j]), 0.f);
    }
}

// ------------------------------------------------- dense edge aggregation
// z[dst] += h[src], 128 channels per edge
__global__ __launch_bounds__(256) void edge_add_k(const float* __restrict__ h,
                                                  const int* __restrict__ src,
                                                  const int* __restrict__ dst,
                                                  float* __restrict__ z, int total)
{
    int stride = gridDim.x * 256;
    for (int i = blockIdx.x * 256 + threadIdx.x; i < total; i += stride) {
        int e = i >> 7, c = i & (HH - 1);
        unsafeAtomicAdd(&z[(long)dst[e] * HH + c], h[(long)src[e] * HH + c]);
    }
}

// ------------------------------------------------------------- 128-GEMM
// out[n][k] = act(bias[k] + sum_j in[n][j] * W[j][k])
// 32-row tiles, 256 threads, each thread a 4x4 micro-tile.
// LDS: W 64KB + in-tile 16KB = 80KB -> 2 blocks/CU.
template<int RELU, int WRITE2, int POOL>
__global__ __launch_bounds__(256) void gemm128_k(
    const float* __restrict__ in, const float* __restrict__ W,
    const float* __restrict__ bias,
    float* __restrict__ out, float* __restrict__ out2,
    const int* __restrict__ batch, float* __restrict__ pooled,
    int ntiles)
{
    __shared__ float Wl[HH * HH];
    __shared__ float inl[32][HH];

    for (int i = threadIdx.x; i < HH * HH; i += 256) Wl[i] = W[i];

    const int tx = threadIdx.x & 31;   // col group: cols 4*tx .. 4*tx+3
    const int ty = threadIdx.x >> 5;   // row group: rows 4*ty .. 4*ty+3
    const int c0 = tx * 4;
    const float4 bb = *(const float4*)&bias[c0];
    __syncthreads();

    for (int tile = blockIdx.x; tile < ntiles; tile += gridDim.x) {
        const int r0 = tile * 32;
        __syncthreads();   // previous tile fully consumed
        {
            const float4* gin = (const float4*)(in + (long)r0 * HH);
            float4* li = (float4*)&inl[0][0];
            #pragma unroll
            for (int i = 0; i < 4; ++i)
                li[threadIdx.x + i * 256] = gin[threadIdx.x + i * 256];
        }
        __syncthreads();

        float acc[4][4];
        #pragma unroll
        for (int i = 0; i < 4; ++i) {
            acc[i][0] = bb.x; acc[i][1] = bb.y; acc[i][2] = bb.z; acc[i][3] = bb.w;
        }

        #pragma unroll 8
        for (int j = 0; j < HH; ++j) {
            const float4 w = *(const float4*)&Wl[j * HH + c0];
            #pragma unroll
            for (int i = 0; i < 4; ++i) {
                const float xv = inl[ty * 4 + i][j];
                acc[i][0] = fmaf(xv, w.x, acc[i][0]);
                acc[i][1] = fmaf(xv, w.y, acc[i][1]);
                acc[i][2] = fmaf(xv, w.z, acc[i][2]);
                acc[i][3] = fmaf(xv, w.w, acc[i][3]);
            }
        }

        #pragma unroll
        for (int i = 0; i < 4; ++i) {
            const int r = r0 + ty * 4 + i;
            float4 v = make_float4(acc[i][0], acc[i][1], acc[i][2], acc[i][3]);
            if (RELU) {
                v.x = fmaxf(v.x, 0.f); v.y = fmaxf(v.y, 0.f);
                v.z = fmaxf(v.z, 0.f); v.w = fmaxf(v.w, 0.f);
            }
            if (POOL) {
                const int g = batch[r];
                float* p = &pooled[(long)g * HH + c0];
                unsafeAtomicAdd(p + 0, v.x);
                unsafeAtomicAdd(p + 1, v.y);
                unsafeAtomicAdd(p + 2, v.z);
                unsafeAtomicAdd(p + 3, v.w);
            } else {
                *(float4*)&out[(long)r * HH + c0] = v;
                if (WRITE2) *(float4*)&out2[(long)r * HH + c0] = v;
            }
        }
    }
}

// ---------------------------------------------------------------- final FC
__global__ __launch_bounds__(128) void fc_k(const float* __restrict__ pooled,
                                            const float* __restrict__ Wfc,
                                            const float* __restrict__ bfc,
                                            float* __restrict__ out)
{
    __shared__ float p[HH];
    const int g = blockIdx.x, k = threadIdx.x;
    p[k] = pooled[g * HH + k];
    __syncthreads();
    float acc = bfc[k];
    #pragma unroll 8
    for (int j = 0; j < HH; ++j) acc = fmaf(p[j], Wfc[j * HH + k], acc);
    out[g * HH + k] = acc;
}

extern "C" void kernel_launch(void* const* d_in, const int* in_sizes, int n_in,
                              void* d_out, int out_size, void* d_ws, size_t ws_size,
                              hipStream_t stream)
{
    const float* x     = (const float*)d_in[0];
    const int*   ei    = (const int*)d_in[1];
    const int*   batch = (const int*)d_in[2];
    const float* W1_0 = (const float*)d_in[3];
    const float* b1_0 = (const float*)d_in[4];
    const float* W2_0 = (const float*)d_in[5];
    const float* b2_0 = (const float*)d_in[6];
    const float* W1_1 = (const float*)d_in[7];
    const float* b1_1 = (const float*)d_in[8];
    const float* W2_1 = (const float*)d_in[9];
    const float* b2_1 = (const float*)d_in[10];
    const float* W1_2 = (const float*)d_in[11];
    const float* b1_2 = (const float*)d_in[12];
    const float* W2_2 = (const float*)d_in[13];
    const float* b2_2 = (const float*)d_in[14];
    const float* Wfc  = (const float*)d_in[15];
    const float* bfc  = (const float*)d_in[16];

    const int N = in_sizes[0];          // 100000
    const int E = in_sizes[1] / 2;      // 640000
    const int* src = ei;
    const int* dst = ei + E;
    const int ntiles = N / 32;          // N % 32 == 0

    float* z      = (float*)d_ws;                 // [N,128]
    float* h      = z + (size_t)N * HH;           // [N,128]
    float* z0     = h + (size_t)N * HH;           // [N]
    float* pooled = z0 + N;                       // [G,128]
    float* outp   = (float*)d_out;

    // layer 0: z0 = x + scatter(x)
    setup_k<<<(N + 255) / 256, 256, 0, stream>>>(x, z0, pooled, N);
    edge0_k<<<(E + 255) / 256, 256, 0, stream>>>(x, src, dst, z0, E);
    // layer 0 MLP: h <- relu(z0*W1_0+b1_0);  h,z <- h@W2_0+b2_0
    expand0_k<<<4096, 256, 0, stream>>>(z0, W1_0, b1_0, h, N * HH);
    gemm128_k<0, 1, 0><<<512, 256, 0, stream>>>(h, W2_0, b2_0, h, z, nullptr, nullptr, ntiles);

    // layer 1
    edge_add_k<<<2048, 256, 0, stream>>>(h, src, dst, z, E * HH);
    gemm128_k<1, 0, 0><<<512, 256, 0, stream>>>(z, W1_1, b1_1, h, nullptr, nullptr, nullptr, ntiles);
    gemm128_k<0, 1, 0><<<512, 256, 0, stream>>>(h, W2_1, b2_1, h, z, nullptr, nullptr, ntiles);

    // layer 2 (pool fused into second GEMM)
    edge_add_k<<<2048, 256, 0, stream>>>(h, src, dst, z, E * HH);
    gemm128_k<1, 0, 0><<<512, 256, 0, stream>>>(z, W1_2, b1_2, h, nullptr, nullptr, nullptr, ntiles);
    gemm128_k<0, 0, 1><<<512, 256, 0, stream>>>(h, W2_2, b2_2, nullptr, nullptr, batch, pooled, ntiles);

    // final FC
    fc_k<<<GG, HH, 0, stream>>>(pooled, Wfc, bfc, outp);
}